// Round 1
// baseline (1081.543 us; speedup 1.0000x reference)
//
#include <hip/hip_runtime.h>
#include <cstddef>

#define HW    16384
#define WROW  128
#define NB    8
#define NC    64
#define CIN   256
#define NOUT  256
#define NPOSF 131072.0f
#define EPSV  1e-5f

// ws layout (float offsets)
#define O_CRS   0      // [64] sum, [64] sumsq
#define O_BN1S  128    // [256] sum (c*4+d), [256] sumsq at +256
#define O_BN2S  640    // [64] sum, [64] sumsq
#define O_MBS   768    // [64] sum, [64] sumsq
#define O_G     896    // [64*64] raw Gram of z
#define O_MZ    4992   // [64] raw sum of z
#define ZERO_FLOATS 5056
#define O_CRWT  5120   // [256][64] transposed cr weights
#define O_WFT   21504  // [64][256] folded ff weights (c-major)
#define O_BF    37888  // [256] folded ff bias
#define O_FRAW  38144  // [8*64*16384] f_raw

// ---------------- transpose cr_w -> [c][o] ----------------
__global__ __launch_bounds__(256) void k_trans(const float* __restrict__ crw,
                                               float* __restrict__ ws) {
  int idx = blockIdx.x * 256 + threadIdx.x;   // 16384
  int c = idx >> 6, o = idx & 63;
  ws[O_CRWT + idx] = crw[o * CIN + c];
}

// ---------------- 1x1 channel reduction GEMM + cr-BN stats ----------------
__global__ __launch_bounds__(256) void k_cr(const float* __restrict__ x,
                                            const float* __restrict__ crwT,
                                            const float* __restrict__ crb,
                                            float* __restrict__ yraw,
                                            float* __restrict__ ws) {
  int p = blockIdx.x * 256 + threadIdx.x;    // 131072 positions
  int b = p >> 14, pix = p & (HW - 1);
  const float* xb = x + (size_t)b * CIN * HW + pix;
  float acc[NC];
#pragma unroll
  for (int o = 0; o < NC; o++) acc[o] = 0.f;
#pragma unroll 4
  for (int c = 0; c < CIN; c++) {
    float xv = xb[(size_t)c * HW];
    const float* wr = crwT + c * NC;
#pragma unroll
    for (int o = 0; o < NC; o++) acc[o] = fmaf(wr[o], xv, acc[o]);
  }
  int lane = threadIdx.x & 63, wid = threadIdx.x >> 6;
  __shared__ float sred[4][128];
  float* yo = yraw + (size_t)b * NC * HW + pix;
#pragma unroll
  for (int o = 0; o < NC; o++) {
    float v = acc[o] + crb[o];
    yo[(size_t)o * HW] = v;
    float s = v, s2 = v * v;
#pragma unroll
    for (int k = 1; k < 64; k <<= 1) { s += __shfl_xor(s, k, 64); s2 += __shfl_xor(s2, k, 64); }
    if (lane == o) { sred[wid][o] = s; sred[wid][64 + o] = s2; }
  }
  __syncthreads();
  if (threadIdx.x < 128) {
    float t = sred[0][threadIdx.x] + sred[1][threadIdx.x] + sred[2][threadIdx.x] + sred[3][threadIdx.x];
    atomicAdd(&ws[O_CRS + threadIdx.x], t);
  }
}

// ---------------- shared dilated-conv helper ----------------
__device__ __forceinline__ void conv4(const float* __restrict__ yb,
                                      const float* __restrict__ dww, int c,
                                      float s1, float t1, int h, int w,
                                      float od[4]) {
  const int DIL[4] = {1, 2, 4, 8};
#pragma unroll
  for (int d = 0; d < 4; d++) {
    int dil = DIL[d];
    const float* kw = dww + (size_t)(d * NC + c) * 9;
    float a = 0.f;
#pragma unroll
    for (int i = 0; i < 3; i++) {
      int hh = h + (i - 1) * dil;
      if ((unsigned)hh < 128u) {
        const float* yr = yb + hh * WROW;
#pragma unroll
        for (int j = 0; j < 3; j++) {
          int wv = w + (j - 1) * dil;
          float kwv = kw[i * 3 + j];
          if ((unsigned)wv < 128u) {
            float yv = yr[wv];
            a = fmaf(kwv, fmaxf(fmaf(s1, yv, t1), 0.f), a);
          }
        }
      }
    }
    od[d] = a;
  }
}

// ---------------- pass A: conv outputs -> bn1 stats only ----------------
__global__ __launch_bounds__(256) void k_dwstats(const float* __restrict__ yraw,
                                                 const float* __restrict__ dww,
                                                 const float* __restrict__ dwb,
                                                 const float* __restrict__ crg,
                                                 const float* __restrict__ crbe,
                                                 float* __restrict__ ws) {
  int blk = blockIdx.x;
  int chunk = blk & 63, c = (blk >> 6) & 63, b = blk >> 12;
  const float inv = 1.0f / NPOSF;
  float m = ws[O_CRS + c] * inv;
  float v = ws[O_CRS + 64 + c] * inv - m * m;
  float s1 = crg[c] * rsqrtf(v + EPSV);
  float t1 = crbe[c] - m * s1;
  const float* yb = yraw + (size_t)(b * NC + c) * HW;
  int pix = chunk * 256 + threadIdx.x;
  int h = pix >> 7, w = pix & 127;
  float od[4];
  conv4(yb, dww, c, s1, t1, h, w, od);
  int lane = threadIdx.x & 63, wid = threadIdx.x >> 6;
  __shared__ float sred[4][8];
#pragma unroll
  for (int d = 0; d < 4; d++) {
    float val = od[d] + dwb[d * NC + c];
    float s = val, s2 = val * val;
#pragma unroll
    for (int k = 1; k < 64; k <<= 1) { s += __shfl_xor(s, k, 64); s2 += __shfl_xor(s2, k, 64); }
    if (lane == 0) { sred[wid][d] = s; sred[wid][4 + d] = s2; }
  }
  __syncthreads();
  if (threadIdx.x < 8) {
    float t = sred[0][threadIdx.x] + sred[1][threadIdx.x] + sred[2][threadIdx.x] + sred[3][threadIdx.x];
    int d = threadIdx.x & 3, which = threadIdx.x >> 2;
    atomicAdd(&ws[O_BN1S + which * 256 + c * 4 + d], t);
  }
}

// ---------------- pass B: conv + bn1 + fuse -> f_raw + bn2 stats ----------------
__global__ __launch_bounds__(256) void k_fuse(const float* __restrict__ yraw,
                                              const float* __restrict__ dww,
                                              const float* __restrict__ dwb,
                                              const float* __restrict__ crg,
                                              const float* __restrict__ crbe,
                                              const float* __restrict__ bn1g,
                                              const float* __restrict__ bn1b,
                                              const float* __restrict__ fusew,
                                              const float* __restrict__ fuseb,
                                              float* __restrict__ ws) {
  int blk = blockIdx.x;
  int chunk = blk & 63, c = (blk >> 6) & 63, b = blk >> 12;
  const float inv = 1.0f / NPOSF;
  float m = ws[O_CRS + c] * inv;
  float v = ws[O_CRS + 64 + c] * inv - m * m;
  float s1 = crg[c] * rsqrtf(v + EPSV);
  float t1 = crbe[c] - m * s1;
  const float* yb = yraw + (size_t)(b * NC + c) * HW;
  int pix = chunk * 256 + threadIdx.x;
  int h = pix >> 7, w = pix & 127;
  float od[4];
  conv4(yb, dww, c, s1, t1, h, w, od);
  float f = fuseb[c];
#pragma unroll
  for (int d = 0; d < 4; d++) {
    float m1 = ws[O_BN1S + c * 4 + d] * inv;
    float v1 = ws[O_BN1S + 256 + c * 4 + d] * inv - m1 * m1;
    float sd = bn1g[c * 4 + d] * rsqrtf(v1 + EPSV);
    float td = bn1b[c * 4 + d] - m1 * sd;
    float val = od[d] + dwb[d * NC + c];
    f = fmaf(fusew[c * 4 + d], fmaxf(fmaf(sd, val, td), 0.f), f);
  }
  ws[O_FRAW + (size_t)(b * NC + c) * HW + pix] = f;
  int lane = threadIdx.x & 63, wid = threadIdx.x >> 6;
  __shared__ float sred[4][2];
  float s = f, s2 = f * f;
#pragma unroll
  for (int k = 1; k < 64; k <<= 1) { s += __shfl_xor(s, k, 64); s2 += __shfl_xor(s2, k, 64); }
  if (lane == 0) { sred[wid][0] = s; sred[wid][1] = s2; }
  __syncthreads();
  if (threadIdx.x < 2) {
    float t = sred[0][threadIdx.x] + sred[1][threadIdx.x] + sred[2][threadIdx.x] + sred[3][threadIdx.x];
    atomicAdd(&ws[O_BN2S + threadIdx.x * 64 + c], t);
  }
}

// ---------------- mb-BN stats on f = relu(bn2(f_raw)) ----------------
__global__ __launch_bounds__(256) void k_mb(const float* __restrict__ bn2g,
                                            const float* __restrict__ bn2b,
                                            float* __restrict__ ws) {
  int blk = blockIdx.x;            // 8192
  int plane = blk >> 4, sub = blk & 15;
  int c = plane & 63;
  const float inv = 1.0f / NPOSF;
  float m = ws[O_BN2S + c] * inv;
  float v = ws[O_BN2S + 64 + c] * inv - m * m;
  float s2v = bn2g[c] * rsqrtf(v + EPSV);
  float t2v = bn2b[c] - m * s2v;
  const float4* fp = (const float4*)(ws + O_FRAW + (size_t)plane * HW + sub * 1024);
  float4 vv = fp[threadIdx.x];
  float s = 0.f, ss = 0.f;
  {
    float f;
    f = fmaxf(fmaf(s2v, vv.x, t2v), 0.f); s += f; ss += f * f;
    f = fmaxf(fmaf(s2v, vv.y, t2v), 0.f); s += f; ss += f * f;
    f = fmaxf(fmaf(s2v, vv.z, t2v), 0.f); s += f; ss += f * f;
    f = fmaxf(fmaf(s2v, vv.w, t2v), 0.f); s += f; ss += f * f;
  }
  int lane = threadIdx.x & 63, wid = threadIdx.x >> 6;
  __shared__ float sred[4][2];
#pragma unroll
  for (int k = 1; k < 64; k <<= 1) { s += __shfl_xor(s, k, 64); ss += __shfl_xor(ss, k, 64); }
  if (lane == 0) { sred[wid][0] = s; sred[wid][1] = ss; }
  __syncthreads();
  if (threadIdx.x < 2) {
    float t = sred[0][threadIdx.x] + sred[1][threadIdx.x] + sred[2][threadIdx.x] + sred[3][threadIdx.x];
    atomicAdd(&ws[O_MBS + threadIdx.x * 64 + c], t);
  }
}

// ---------------- Gram of z + mean of z (for analytic final BN) ----------------
__global__ __launch_bounds__(256) void k_gram(const float* __restrict__ bn2g,
                                              const float* __restrict__ bn2b,
                                              const float* __restrict__ mbg,
                                              const float* __restrict__ mbb,
                                              float* __restrict__ ws) {
  __shared__ float zt[NC * 256];
  __shared__ float msum[4][NC];
  int tid = threadIdx.x, lane = tid & 63, wid = tid >> 6;
  int tile = blockIdx.x & 63, b = blockIdx.x >> 6;
  const float* fb = ws + O_FRAW + (size_t)b * NC * HW + tile * 256;
  const float inv = 1.0f / NPOSF;
  for (int c = 0; c < NC; c++) {
    float m2 = ws[O_BN2S + c] * inv;
    float v2 = ws[O_BN2S + 64 + c] * inv - m2 * m2;
    float s2v = bn2g[c] * rsqrtf(v2 + EPSV);
    float t2v = bn2b[c] - m2 * s2v;
    float m3 = ws[O_MBS + c] * inv;
    float v3 = ws[O_MBS + 64 + c] * inv - m3 * m3;
    float s3v = mbg[c] * rsqrtf(v3 + EPSV);
    float t3v = mbb[c] - m3 * s3v;
    float fv = fb[(size_t)c * HW + tid];
    float z = fmaxf(fmaf(s3v, fmaxf(fmaf(s2v, fv, t2v), 0.f), t3v), 0.f);
    zt[c * 256 + (tid ^ ((((unsigned)c >> 2) & 7u) << 2))] = z;
    float s = z;
#pragma unroll
    for (int k = 1; k < 64; k <<= 1) s += __shfl_xor(s, k, 64);
    if (lane == 0) msum[wid][c] = s;
  }
  __syncthreads();
  if (tid < NC) {
    float t = msum[0][tid] + msum[1][tid] + msum[2][tid] + msum[3][tid];
    atomicAdd(&ws[O_MZ + tid], t);
  }
  int tr = (tid & 15) * 4, tc = (tid >> 4) * 4;
  float g[4][4];
#pragma unroll
  for (int i = 0; i < 4; i++)
#pragma unroll
    for (int j = 0; j < 4; j++) g[i][j] = 0.f;
  for (int p = 0; p < 256; p += 4) {
    float4 av[4], bv[4];
#pragma unroll
    for (int i = 0; i < 4; i++) {
      int ca = tr + i, cb = tc + i;
      av[i] = *(const float4*)&zt[ca * 256 + (p ^ ((((unsigned)ca >> 2) & 7u) << 2))];
      bv[i] = *(const float4*)&zt[cb * 256 + (p ^ ((((unsigned)cb >> 2) & 7u) << 2))];
    }
#pragma unroll
    for (int i = 0; i < 4; i++)
#pragma unroll
      for (int j = 0; j < 4; j++) {
        g[i][j] = fmaf(av[i].x, bv[j].x, g[i][j]);
        g[i][j] = fmaf(av[i].y, bv[j].y, g[i][j]);
        g[i][j] = fmaf(av[i].z, bv[j].z, g[i][j]);
        g[i][j] = fmaf(av[i].w, bv[j].w, g[i][j]);
      }
  }
#pragma unroll
  for (int i = 0; i < 4; i++)
#pragma unroll
    for (int j = 0; j < 4; j++)
      atomicAdd(&ws[O_G + (tr + i) * 64 + (tc + j)], g[i][j]);
}

// ---------------- analytic ffbn + weight folding ----------------
__global__ __launch_bounds__(256) void k_fold(const float* __restrict__ ffw,
                                              const float* __restrict__ ffb,
                                              const float* __restrict__ ffg,
                                              const float* __restrict__ ffbe,
                                              float* __restrict__ ws) {
  int oc = threadIdx.x;
  const float inv = 1.0f / NPOSF;
  float wm = 0.f;
#pragma unroll 8
  for (int c = 0; c < NC; c++) wm = fmaf(ffw[oc * NC + c], ws[O_MZ + c] * inv, wm);
  float bias = ffb[oc];
  float mo = wm + bias;
  float e2s = 0.f;
  for (int c1 = 0; c1 < NC; c1++) {
    float w1 = ffw[oc * NC + c1];
    const float* gr = ws + O_G + c1 * NC;
    float t = 0.f;
#pragma unroll 8
    for (int c2 = 0; c2 < NC; c2++) t = fmaf(ffw[oc * NC + c2], gr[c2], t);
    e2s = fmaf(w1, t, e2s);
  }
  float e2 = e2s * inv + 2.f * bias * wm + bias * bias;
  float var = e2 - mo * mo;
  float s4 = ffg[oc] * rsqrtf(var + EPSV);
  float t4 = ffbe[oc] - mo * s4;
#pragma unroll
  for (int c = 0; c < NC; c++) ws[O_WFT + c * NOUT + oc] = s4 * ffw[oc * NC + c];
  ws[O_BF + oc] = fmaf(s4, bias, t4);
}

// ---------------- final: z -> folded 1x1 GEMM -> relu -> out ----------------
__global__ __launch_bounds__(256) void k_final(const float* __restrict__ bn2g,
                                               const float* __restrict__ bn2b,
                                               const float* __restrict__ mbg,
                                               const float* __restrict__ mbb,
                                               float* __restrict__ out,
                                               const float* __restrict__ ws) {
  __shared__ float zs[NC * 256];
  int tid = threadIdx.x;
  int p = blockIdx.x * 256 + tid;
  int b = p >> 14, pix = p & (HW - 1);
  const float* fb = ws + O_FRAW + (size_t)b * NC * HW + pix;
  const float inv = 1.0f / NPOSF;
  for (int c = 0; c < NC; c++) {
    float m2 = ws[O_BN2S + c] * inv;
    float v2 = ws[O_BN2S + 64 + c] * inv - m2 * m2;
    float s2v = bn2g[c] * rsqrtf(v2 + EPSV);
    float t2v = bn2b[c] - m2 * s2v;
    float m3 = ws[O_MBS + c] * inv;
    float v3 = ws[O_MBS + 64 + c] * inv - m3 * m3;
    float s3v = mbg[c] * rsqrtf(v3 + EPSV);
    float t3v = mbb[c] - m3 * s3v;
    float fv = fb[(size_t)c * HW];
    zs[c * 256 + tid] = fmaxf(fmaf(s3v, fmaxf(fmaf(s2v, fv, t2v), 0.f), t3v), 0.f);
  }
  // per-thread private LDS scratch: no cross-thread sharing, no barrier needed
  float* ob = out + (size_t)b * NOUT * HW + pix;
  for (int ch = 0; ch < 4; ch++) {
    float acc[64];
#pragma unroll
    for (int j = 0; j < 64; j++) acc[j] = 0.f;
    const float* wf = ws + O_WFT + ch * 64;
    for (int c = 0; c < NC; c++) {
      float zv = zs[c * 256 + tid];
      const float* wr = wf + c * NOUT;
#pragma unroll
      for (int j = 0; j < 64; j++) acc[j] = fmaf(wr[j], zv, acc[j]);
    }
#pragma unroll
    for (int j = 0; j < 64; j++) {
      int oc = ch * 64 + j;
      ob[(size_t)oc * HW] = fmaxf(acc[j] + ws[O_BF + oc], 0.f);
    }
  }
}

extern "C" void kernel_launch(void* const* d_in, const int* in_sizes, int n_in,
                              void* d_out, int out_size, void* d_ws, size_t ws_size,
                              hipStream_t stream) {
  (void)in_sizes; (void)n_in; (void)out_size; (void)ws_size;
  const float* x     = (const float*)d_in[0];
  const float* crw   = (const float*)d_in[1];
  const float* crb   = (const float*)d_in[2];
  const float* crg   = (const float*)d_in[3];
  const float* crbe  = (const float*)d_in[4];
  const float* dww   = (const float*)d_in[5];
  const float* dwb   = (const float*)d_in[6];
  const float* bn1g  = (const float*)d_in[7];
  const float* bn1b  = (const float*)d_in[8];
  const float* fusew = (const float*)d_in[9];
  const float* fuseb = (const float*)d_in[10];
  const float* bn2g  = (const float*)d_in[11];
  const float* bn2b  = (const float*)d_in[12];
  const float* mbg   = (const float*)d_in[13];
  const float* mbb   = (const float*)d_in[14];
  const float* ffw   = (const float*)d_in[15];
  const float* ffb   = (const float*)d_in[16];
  const float* ffg   = (const float*)d_in[17];
  const float* ffbe  = (const float*)d_in[18];
  float* out = (float*)d_out;
  float* ws  = (float*)d_ws;
  float* yraw = out;  // first 8.4M floats of d_out used as scratch for y_raw

  hipMemsetAsync(ws, 0, ZERO_FLOATS * sizeof(float), stream);
  k_trans<<<64, 256, 0, stream>>>(crw, ws);
  k_cr<<<512, 256, 0, stream>>>(x, ws + O_CRWT, crb, yraw, ws);
  k_dwstats<<<32768, 256, 0, stream>>>(yraw, dww, dwb, crg, crbe, ws);
  k_fuse<<<32768, 256, 0, stream>>>(yraw, dww, dwb, crg, crbe, bn1g, bn1b, fusew, fuseb, ws);
  k_mb<<<8192, 256, 0, stream>>>(bn2g, bn2b, ws);
  k_gram<<<512, 256, 0, stream>>>(bn2g, bn2b, mbg, mbb, ws);
  k_fold<<<1, 256, 0, stream>>>(ffw, ffb, ffg, ffbe, ws);
  k_final<<<512, 256, 0, stream>>>(bn2g, bn2b, mbg, mbb, out, ws);
}

// Round 3
// 730.763 us; speedup vs baseline: 1.4800x; 1.4800x over previous
//
#include <hip/hip_runtime.h>
#include <cstddef>

#define HW    16384
#define WROW  128
#define NB    8
#define NC    64
#define CIN   256
#define NOUT  256
#define NPOSF 131072.0f
#define EPSV  1e-5f

// ws layout (float offsets)
#define O_CRS   0      // [64] sum, [64] sumsq
#define O_BN1S  128    // [256] sum (c*4+d), [256] sumsq at +256
#define O_BN2S  640    // [64] sum, [64] sumsq
#define O_MBS   768    // [64] sum, [64] sumsq
#define O_G     896    // [64*64] raw Gram of z
#define O_MZ    4992   // [64] raw sum of z
#define ZERO_FLOATS 5056
#define O_CRWT  5120   // [256][64] transposed cr weights
#define O_WFT   21504  // [64][256] folded ff weights (c-major)
#define O_BF    37888  // [256] folded ff bias
#define O_FRAW  38144  // [8*64*16384] f_raw

#define LROW 144       // padded LDS row stride (8 left pad + 128 + 8 right pad)
#define LROWS 80       // 64 rows + 8 halo each side

// ---------------- transpose cr_w -> [c][o] ----------------
__global__ __launch_bounds__(256) void k_trans(const float* __restrict__ crw,
                                               float* __restrict__ ws) {
  int idx = blockIdx.x * 256 + threadIdx.x;   // 16384
  int c = idx >> 6, o = idx & 63;
  ws[O_CRWT + idx] = crw[o * CIN + c];
}

// ---------------- 1x1 channel reduction GEMM + cr-BN stats ----------------
__global__ __launch_bounds__(256) void k_cr(const float* __restrict__ x,
                                            const float* __restrict__ crwT,
                                            const float* __restrict__ crb,
                                            float* __restrict__ yraw,
                                            float* __restrict__ ws) {
  int p = blockIdx.x * 256 + threadIdx.x;    // 131072 positions
  int b = p >> 14, pix = p & (HW - 1);
  const float* xb = x + (size_t)b * CIN * HW + pix;
  float acc[NC];
#pragma unroll
  for (int o = 0; o < NC; o++) acc[o] = 0.f;
#pragma unroll 4
  for (int c = 0; c < CIN; c++) {
    float xv = xb[(size_t)c * HW];
    const float* wr = crwT + c * NC;
#pragma unroll
    for (int o = 0; o < NC; o++) acc[o] = fmaf(wr[o], xv, acc[o]);
  }
  int lane = threadIdx.x & 63, wid = threadIdx.x >> 6;
  __shared__ float sred[4][128];
  float* yo = yraw + (size_t)b * NC * HW + pix;
#pragma unroll
  for (int o = 0; o < NC; o++) {
    float v = acc[o] + crb[o];
    yo[(size_t)o * HW] = v;
    float s = v, s2 = v * v;
#pragma unroll
    for (int k = 1; k < 64; k <<= 1) { s += __shfl_xor(s, k, 64); s2 += __shfl_xor(s2, k, 64); }
    if (lane == o) { sred[wid][o] = s; sred[wid][64 + o] = s2; }
  }
  __syncthreads();
  if (threadIdx.x < 128) {
    float t = sred[0][threadIdx.x] + sred[1][threadIdx.x] + sred[2][threadIdx.x] + sred[3][threadIdx.x];
    atomicAdd(&ws[O_CRS + threadIdx.x], t);
  }
}

// ---------------- LDS-tiled multi-dilation conv (MODE 0: bn1 stats, MODE 1: fuse) ----------------
template<int MODE>
__global__ __launch_bounds__(256) void k_conv(const float* __restrict__ yraw,
                                              const float* __restrict__ dww,
                                              const float* __restrict__ dwb,
                                              const float* __restrict__ crg,
                                              const float* __restrict__ crbe,
                                              const float* __restrict__ bn1g,
                                              const float* __restrict__ bn1b,
                                              const float* __restrict__ fusew,
                                              const float* __restrict__ fuseb,
                                              float* __restrict__ ws) {
  __shared__ float lds[LROWS * LROW];
  int blk = blockIdx.x;                       // 1024 = 8b * 64c * 2 halves
  int half = blk & 1, c = (blk >> 1) & 63, b = blk >> 7;
  int tid = threadIdx.x;
  const float inv = 1.0f / NPOSF;

  // cr-BN fold
  float m = ws[O_CRS + c] * inv;
  float v = ws[O_CRS + 64 + c] * inv - m * m;
  float s1 = crg[c] * rsqrtf(v + EPSV);
  float t1 = crbe[c] - m * s1;

  // conv weights + biases (wave-uniform)
  float kw[36];
#pragma unroll
  for (int d = 0; d < 4; d++)
#pragma unroll
    for (int t = 0; t < 9; t++) kw[d * 9 + t] = dww[((size_t)d * NC + c) * 9 + t];
  float bias[4];
#pragma unroll
  for (int d = 0; d < 4; d++) bias[d] = dwb[d * NC + c];

  // FUSE-mode folded bn1 params
  float fw[4], sdv[4], tdd[4], fb0 = 0.f;
  if (MODE == 1) {
#pragma unroll
    for (int d = 0; d < 4; d++) {
      float m1 = ws[O_BN1S + c * 4 + d] * inv;
      float v1 = ws[O_BN1S + 256 + c * 4 + d] * inv - m1 * m1;
      float sd = bn1g[c * 4 + d] * rsqrtf(v1 + EPSV);
      float td = bn1b[c * 4 + d] - m1 * sd;
      sdv[d] = sd;
      tdd[d] = fmaf(sd, bias[d], td);   // fold conv bias into bn1 shift
      fw[d] = fusew[c * 4 + d];
    }
    fb0 = fuseb[c];
  }

  // ---- stage: zero pads, then load 80 rows (halo clipped) with relu(bn) applied ----
  float4* lds4 = (float4*)lds;
#pragma unroll
  for (int k = 0; k < 12; k++) {
    int i = tid + k * 256;
    if (i < (LROWS * LROW) / 4) lds4[i] = make_float4(0.f, 0.f, 0.f, 0.f);
  }
  __syncthreads();
  int r0 = half * 64;
  const float4* yb4 = (const float4*)(yraw + (size_t)(b * NC + c) * HW);
#pragma unroll
  for (int k = 0; k < 10; k++) {
    int j = tid + k * 256;          // 2560 float4 = 80 rows * 32
    int l = j >> 5, c4 = j & 31;
    int g = r0 - 8 + l;
    if ((unsigned)g < 128u) {
      float4 vv = yb4[g * 32 + c4];
      vv.x = fmaxf(fmaf(s1, vv.x, t1), 0.f);
      vv.y = fmaxf(fmaf(s1, vv.y, t1), 0.f);
      vv.z = fmaxf(fmaf(s1, vv.z, t1), 0.f);
      vv.w = fmaxf(fmaf(s1, vv.w, t1), 0.f);
      *(float4*)&lds[l * LROW + 8 + c4 * 4] = vv;
    }
  }
  __syncthreads();

  // ---- compute: each thread 8 row-iters x 4 consecutive pixels ----
  int w0 = (tid & 31) * 4, h0 = tid >> 5, cb = w0 + 8;
  const int DIL[4] = {1, 2, 4, 8};

  float ss[4] = {0.f, 0.f, 0.f, 0.f}, s2[4] = {0.f, 0.f, 0.f, 0.f};  // stats mode
  float fs = 0.f, fs2 = 0.f;                                          // fuse mode
  float* fout = ws + O_FRAW + (size_t)(b * NC + c) * HW;

  for (int k = 0; k < 8; k++) {
    int lh = h0 + 8 * k;            // local row 0..63
    int r = lh + 8;                 // LDS row
    float od[4][4];
#pragma unroll
    for (int d = 0; d < 4; d++)
#pragma unroll
      for (int j = 0; j < 4; j++) od[d][j] = 0.f;

    // center row: 5 windows covering cb-8 .. cb+11
    {
      float4 A = *(const float4*)&lds[r * LROW + cb - 8];
      float4 B = *(const float4*)&lds[r * LROW + cb - 4];
      float4 C = *(const float4*)&lds[r * LROW + cb];
      float4 D = *(const float4*)&lds[r * LROW + cb + 4];
      float4 E = *(const float4*)&lds[r * LROW + cb + 8];
      float seg[20] = {A.x, A.y, A.z, A.w, B.x, B.y, B.z, B.w,
                       C.x, C.y, C.z, C.w, D.x, D.y, D.z, D.w,
                       E.x, E.y, E.z, E.w};
#pragma unroll
      for (int d = 0; d < 4; d++) {
        int dil = DIL[d];
#pragma unroll
        for (int j = 0; j < 4; j++) {
          float a = od[d][j];
          a = fmaf(kw[d * 9 + 3], seg[8 + j - dil], a);
          a = fmaf(kw[d * 9 + 4], seg[8 + j], a);
          a = fmaf(kw[d * 9 + 5], seg[8 + j + dil], a);
          od[d][j] = a;
        }
      }
    }
    // rows +-1, +-2, +-4: windows cb-4, cb, cb+4
#pragma unroll
    for (int di = 0; di < 3; di++) {
      int off = DIL[di];
#pragma unroll
      for (int sgn = 0; sgn < 2; sgn++) {
        int r2 = sgn ? r + off : r - off;
        int krow = sgn ? 6 : 0;
        float4 A = *(const float4*)&lds[r2 * LROW + cb - 4];
        float4 B = *(const float4*)&lds[r2 * LROW + cb];
        float4 C = *(const float4*)&lds[r2 * LROW + cb + 4];
        float sg[12] = {A.x, A.y, A.z, A.w, B.x, B.y, B.z, B.w, C.x, C.y, C.z, C.w};
#pragma unroll
        for (int j = 0; j < 4; j++) {
          float a = od[di][j];
          a = fmaf(kw[di * 9 + krow + 0], sg[j + 4 - off], a);
          a = fmaf(kw[di * 9 + krow + 1], sg[j + 4], a);
          a = fmaf(kw[di * 9 + krow + 2], sg[j + 4 + off], a);
          od[di][j] = a;
        }
      }
    }
    // rows +-8 (d=3): windows cb-8, cb, cb+8
#pragma unroll
    for (int sgn = 0; sgn < 2; sgn++) {
      int r2 = sgn ? r + 8 : r - 8;
      int krow = sgn ? 6 : 0;
      float4 A = *(const float4*)&lds[r2 * LROW + cb - 8];
      float4 B = *(const float4*)&lds[r2 * LROW + cb];
      float4 C = *(const float4*)&lds[r2 * LROW + cb + 8];
      float av[4] = {A.x, A.y, A.z, A.w};
      float bv[4] = {B.x, B.y, B.z, B.w};
      float cv[4] = {C.x, C.y, C.z, C.w};
#pragma unroll
      for (int j = 0; j < 4; j++) {
        float a = od[3][j];
        a = fmaf(kw[27 + krow + 0], av[j], a);
        a = fmaf(kw[27 + krow + 1], bv[j], a);
        a = fmaf(kw[27 + krow + 2], cv[j], a);
        od[3][j] = a;
      }
    }

    if (MODE == 0) {
#pragma unroll
      for (int d = 0; d < 4; d++)
#pragma unroll
        for (int j = 0; j < 4; j++) {
          float val = od[d][j] + bias[d];
          ss[d] += val;
          s2[d] += val * val;
        }
    } else {
      float4 f4;
      float fj[4];
#pragma unroll
      for (int j = 0; j < 4; j++) {
        float f = fb0;
#pragma unroll
        for (int d = 0; d < 4; d++)
          f = fmaf(fw[d], fmaxf(fmaf(sdv[d], od[d][j], tdd[d]), 0.f), f);
        fj[j] = f;
        fs += f;
        fs2 += f * f;
      }
      f4.x = fj[0]; f4.y = fj[1]; f4.z = fj[2]; f4.w = fj[3];
      *(float4*)&fout[(r0 + lh) * WROW + w0] = f4;
    }
  }

  // ---- reductions ----
  int lane = tid & 63, wid = tid >> 6;
  if (MODE == 0) {
    __shared__ float sred[4][8];
#pragma unroll
    for (int d = 0; d < 4; d++) {
      float s = ss[d], q = s2[d];
#pragma unroll
      for (int k = 1; k < 64; k <<= 1) { s += __shfl_xor(s, k, 64); q += __shfl_xor(q, k, 64); }
      if (lane == 0) { sred[wid][d] = s; sred[wid][4 + d] = q; }
    }
    __syncthreads();
    if (tid < 8) {
      float t = sred[0][tid] + sred[1][tid] + sred[2][tid] + sred[3][tid];
      int d = tid & 3, which = tid >> 2;
      atomicAdd(&ws[O_BN1S + which * 256 + c * 4 + d], t);
    }
  } else {
    __shared__ float sred[4][2];
    float s = fs, q = fs2;
#pragma unroll
    for (int k = 1; k < 64; k <<= 1) { s += __shfl_xor(s, k, 64); q += __shfl_xor(q, k, 64); }
    if (lane == 0) { sred[wid][0] = s; sred[wid][1] = q; }
    __syncthreads();
    if (tid < 2) {
      float t = sred[0][tid] + sred[1][tid] + sred[2][tid] + sred[3][tid];
      atomicAdd(&ws[O_BN2S + tid * 64 + c], t);
    }
  }
}

// ---------------- mb-BN stats on f = relu(bn2(f_raw)) ----------------
__global__ __launch_bounds__(256) void k_mb(const float* __restrict__ bn2g,
                                            const float* __restrict__ bn2b,
                                            float* __restrict__ ws) {
  int blk = blockIdx.x;            // 8192
  int plane = blk >> 4, sub = blk & 15;
  int c = plane & 63;
  const float inv = 1.0f / NPOSF;
  float m = ws[O_BN2S + c] * inv;
  float v = ws[O_BN2S + 64 + c] * inv - m * m;
  float s2v = bn2g[c] * rsqrtf(v + EPSV);
  float t2v = bn2b[c] - m * s2v;
  const float4* fp = (const float4*)(ws + O_FRAW + (size_t)plane * HW + sub * 1024);
  float4 vv = fp[threadIdx.x];
  float s = 0.f, ss = 0.f;
  {
    float f;
    f = fmaxf(fmaf(s2v, vv.x, t2v), 0.f); s += f; ss += f * f;
    f = fmaxf(fmaf(s2v, vv.y, t2v), 0.f); s += f; ss += f * f;
    f = fmaxf(fmaf(s2v, vv.z, t2v), 0.f); s += f; ss += f * f;
    f = fmaxf(fmaf(s2v, vv.w, t2v), 0.f); s += f; ss += f * f;
  }
  int lane = threadIdx.x & 63, wid = threadIdx.x >> 6;
  __shared__ float sred[4][2];
#pragma unroll
  for (int k = 1; k < 64; k <<= 1) { s += __shfl_xor(s, k, 64); ss += __shfl_xor(ss, k, 64); }
  if (lane == 0) { sred[wid][0] = s; sred[wid][1] = ss; }
  __syncthreads();
  if (threadIdx.x < 2) {
    float t = sred[0][threadIdx.x] + sred[1][threadIdx.x] + sred[2][threadIdx.x] + sred[3][threadIdx.x];
    atomicAdd(&ws[O_MBS + threadIdx.x * 64 + c], t);
  }
}

// ---------------- Gram of z + mean of z (for analytic final BN) ----------------
__global__ __launch_bounds__(256) void k_gram(const float* __restrict__ bn2g,
                                              const float* __restrict__ bn2b,
                                              const float* __restrict__ mbg,
                                              const float* __restrict__ mbb,
                                              float* __restrict__ ws) {
  __shared__ float zt[NC * 256];
  __shared__ float msum[4][NC];
  int tid = threadIdx.x, lane = tid & 63, wid = tid >> 6;
  int tile = blockIdx.x & 63, b = blockIdx.x >> 6;
  const float* fb = ws + O_FRAW + (size_t)b * NC * HW + tile * 256;
  const float inv = 1.0f / NPOSF;
  for (int c = 0; c < NC; c++) {
    float m2 = ws[O_BN2S + c] * inv;
    float v2 = ws[O_BN2S + 64 + c] * inv - m2 * m2;
    float s2v = bn2g[c] * rsqrtf(v2 + EPSV);
    float t2v = bn2b[c] - m2 * s2v;
    float m3 = ws[O_MBS + c] * inv;
    float v3 = ws[O_MBS + 64 + c] * inv - m3 * m3;
    float s3v = mbg[c] * rsqrtf(v3 + EPSV);
    float t3v = mbb[c] - m3 * s3v;
    float fv = fb[(size_t)c * HW + tid];
    float z = fmaxf(fmaf(s3v, fmaxf(fmaf(s2v, fv, t2v), 0.f), t3v), 0.f);
    zt[c * 256 + (tid ^ ((((unsigned)c >> 2) & 7u) << 2))] = z;
    float s = z;
#pragma unroll
    for (int k = 1; k < 64; k <<= 1) s += __shfl_xor(s, k, 64);
    if (lane == 0) msum[wid][c] = s;
  }
  __syncthreads();
  if (tid < NC) {
    float t = msum[0][tid] + msum[1][tid] + msum[2][tid] + msum[3][tid];
    atomicAdd(&ws[O_MZ + tid], t);
  }
  int tr = (tid & 15) * 4, tc = (tid >> 4) * 4;
  float g[4][4];
#pragma unroll
  for (int i = 0; i < 4; i++)
#pragma unroll
    for (int j = 0; j < 4; j++) g[i][j] = 0.f;
  for (int p = 0; p < 256; p += 4) {
    float4 av[4], bv[4];
#pragma unroll
    for (int i = 0; i < 4; i++) {
      int ca = tr + i, cb = tc + i;
      av[i] = *(const float4*)&zt[ca * 256 + (p ^ ((((unsigned)ca >> 2) & 7u) << 2))];
      bv[i] = *(const float4*)&zt[cb * 256 + (p ^ ((((unsigned)cb >> 2) & 7u) << 2))];
    }
#pragma unroll
    for (int i = 0; i < 4; i++)
#pragma unroll
      for (int j = 0; j < 4; j++) {
        g[i][j] = fmaf(av[i].x, bv[j].x, g[i][j]);
        g[i][j] = fmaf(av[i].y, bv[j].y, g[i][j]);
        g[i][j] = fmaf(av[i].z, bv[j].z, g[i][j]);
        g[i][j] = fmaf(av[i].w, bv[j].w, g[i][j]);
      }
  }
#pragma unroll
  for (int i = 0; i < 4; i++)
#pragma unroll
    for (int j = 0; j < 4; j++)
      atomicAdd(&ws[O_G + (tr + i) * 64 + (tc + j)], g[i][j]);
}

// ---------------- analytic ffbn + weight folding ----------------
__global__ __launch_bounds__(256) void k_fold(const float* __restrict__ ffw,
                                              const float* __restrict__ ffb,
                                              const float* __restrict__ ffg,
                                              const float* __restrict__ ffbe,
                                              float* __restrict__ ws) {
  int oc = threadIdx.x;
  const float inv = 1.0f / NPOSF;
  float wm = 0.f;
#pragma unroll 8
  for (int c = 0; c < NC; c++) wm = fmaf(ffw[oc * NC + c], ws[O_MZ + c] * inv, wm);
  float bias = ffb[oc];
  float mo = wm + bias;
  float e2s = 0.f;
  for (int c1 = 0; c1 < NC; c1++) {
    float w1 = ffw[oc * NC + c1];
    const float* gr = ws + O_G + c1 * NC;
    float t = 0.f;
#pragma unroll 8
    for (int c2 = 0; c2 < NC; c2++) t = fmaf(ffw[oc * NC + c2], gr[c2], t);
    e2s = fmaf(w1, t, e2s);
  }
  float e2 = e2s * inv + 2.f * bias * wm + bias * bias;
  float var = e2 - mo * mo;
  float s4 = ffg[oc] * rsqrtf(var + EPSV);
  float t4 = ffbe[oc] - mo * s4;
#pragma unroll
  for (int c = 0; c < NC; c++) ws[O_WFT + c * NOUT + oc] = s4 * ffw[oc * NC + c];
  ws[O_BF + oc] = fmaf(s4, bias, t4);
}

// ---------------- final: z -> folded 1x1 GEMM -> relu -> out ----------------
__global__ __launch_bounds__(256) void k_final(const float* __restrict__ bn2g,
                                               const float* __restrict__ bn2b,
                                               const float* __restrict__ mbg,
                                               const float* __restrict__ mbb,
                                               float* __restrict__ out,
                                               const float* __restrict__ ws) {
  __shared__ float zs[NC * 256];
  int tid = threadIdx.x;
  int p = blockIdx.x * 256 + tid;
  int b = p >> 14, pix = p & (HW - 1);
  const float* fb = ws + O_FRAW + (size_t)b * NC * HW + pix;
  const float inv = 1.0f / NPOSF;
  for (int c = 0; c < NC; c++) {
    float m2 = ws[O_BN2S + c] * inv;
    float v2 = ws[O_BN2S + 64 + c] * inv - m2 * m2;
    float s2v = bn2g[c] * rsqrtf(v2 + EPSV);
    float t2v = bn2b[c] - m2 * s2v;
    float m3 = ws[O_MBS + c] * inv;
    float v3 = ws[O_MBS + 64 + c] * inv - m3 * m3;
    float s3v = mbg[c] * rsqrtf(v3 + EPSV);
    float t3v = mbb[c] - m3 * s3v;
    float fv = fb[(size_t)c * HW];
    zs[c * 256 + tid] = fmaxf(fmaf(s3v, fmaxf(fmaf(s2v, fv, t2v), 0.f), t3v), 0.f);
  }
  float* ob = out + (size_t)b * NOUT * HW + pix;
  for (int ch = 0; ch < 4; ch++) {
    float acc[64];
#pragma unroll
    for (int j = 0; j < 64; j++) acc[j] = 0.f;
    const float* wf = ws + O_WFT + ch * 64;
    for (int c = 0; c < NC; c++) {
      float zv = zs[c * 256 + tid];
      const float* wr = wf + c * NOUT;
#pragma unroll
      for (int j = 0; j < 64; j++) acc[j] = fmaf(wr[j], zv, acc[j]);
    }
#pragma unroll
    for (int j = 0; j < 64; j++) {
      int oc = ch * 64 + j;
      ob[(size_t)oc * HW] = fmaxf(acc[j] + ws[O_BF + oc], 0.f);
    }
  }
}

extern "C" void kernel_launch(void* const* d_in, const int* in_sizes, int n_in,
                              void* d_out, int out_size, void* d_ws, size_t ws_size,
                              hipStream_t stream) {
  (void)in_sizes; (void)n_in; (void)out_size; (void)ws_size;
  const float* x     = (const float*)d_in[0];
  const float* crw   = (const float*)d_in[1];
  const float* crb   = (const float*)d_in[2];
  const float* crg   = (const float*)d_in[3];
  const float* crbe  = (const float*)d_in[4];
  const float* dww   = (const float*)d_in[5];
  const float* dwb   = (const float*)d_in[6];
  const float* bn1g  = (const float*)d_in[7];
  const float* bn1b  = (const float*)d_in[8];
  const float* fusew = (const float*)d_in[9];
  const float* fuseb = (const float*)d_in[10];
  const float* bn2g  = (const float*)d_in[11];
  const float* bn2b  = (const float*)d_in[12];
  const float* mbg   = (const float*)d_in[13];
  const float* mbb   = (const float*)d_in[14];
  const float* ffw   = (const float*)d_in[15];
  const float* ffb   = (const float*)d_in[16];
  const float* ffg   = (const float*)d_in[17];
  const float* ffbe  = (const float*)d_in[18];
  float* out = (float*)d_out;
  float* ws  = (float*)d_ws;
  float* yraw = out;  // first 8.4M floats of d_out used as scratch for y_raw

  hipMemsetAsync(ws, 0, ZERO_FLOATS * sizeof(float), stream);
  k_trans<<<64, 256, 0, stream>>>(crw, ws);
  k_cr<<<512, 256, 0, stream>>>(x, ws + O_CRWT, crb, yraw, ws);
  k_conv<0><<<1024, 256, 0, stream>>>(yraw, dww, dwb, crg, crbe, bn1g, bn1b, fusew, fuseb, ws);
  k_conv<1><<<1024, 256, 0, stream>>>(yraw, dww, dwb, crg, crbe, bn1g, bn1b, fusew, fuseb, ws);
  k_mb<<<8192, 256, 0, stream>>>(bn2g, bn2b, ws);
  k_gram<<<512, 256, 0, stream>>>(bn2g, bn2b, mbg, mbb, ws);
  k_fold<<<1, 256, 0, stream>>>(ffw, ffb, ffg, ffbe, ws);
  k_final<<<512, 256, 0, stream>>>(bn2g, bn2b, mbg, mbb, out, ws);
}

// Round 6
// 640.393 us; speedup vs baseline: 1.6889x; 1.1411x over previous
//
#include <hip/hip_runtime.h>
#include <cstddef>

#define HW    16384
#define WROW  128
#define NB    8
#define NC    64
#define CIN   256
#define NOUT  256
#define NPOSF 131072.0f
#define EPSV  1e-5f

// ws layout (float offsets)
#define O_CRS   0      // [64] sum, [64] sumsq
#define O_BN1S  128    // [256] sum (c*4+d), [256] sumsq at +256
#define O_BN2S  640    // [64] sum, [64] sumsq
#define O_MBS   768    // [64] sum, [64] sumsq
#define O_G     896    // [64*64] raw Gram of z
#define O_MZ    4992   // [64] raw sum of z
#define ZERO_FLOATS 5056
#define O_CRWT  5120   // [256][64] transposed cr weights
#define O_WFT   21504  // [64][256] folded ff weights (c-major)
#define O_BF    37888  // [256] folded ff bias
#define O_FRAW  38144  // [8*64*16384] f_raw

#define LROW 144       // padded LDS row stride (8 left pad + 128 + 8 right pad)
#define LROWS 80       // 64 rows + 8 halo each side

// ---------------- transpose cr_w -> [c][o] ----------------
__global__ __launch_bounds__(256) void k_trans(const float* __restrict__ crw,
                                               float* __restrict__ ws) {
  int idx = blockIdx.x * 256 + threadIdx.x;   // 16384
  int c = idx >> 6, o = idx & 63;
  ws[O_CRWT + idx] = crw[o * CIN + c];
}

// ---------------- 1x1 channel reduction GEMM + cr-BN stats ----------------
__global__ __launch_bounds__(256) void k_cr(const float* __restrict__ x,
                                            const float* __restrict__ crwT,
                                            const float* __restrict__ crb,
                                            float* __restrict__ yraw,
                                            float* __restrict__ ws) {
  int p = blockIdx.x * 256 + threadIdx.x;    // 131072 positions
  int b = p >> 14, pix = p & (HW - 1);
  const float* xb = x + (size_t)b * CIN * HW + pix;
  float acc[NC];
#pragma unroll
  for (int o = 0; o < NC; o++) acc[o] = 0.f;
#pragma unroll 4
  for (int c = 0; c < CIN; c++) {
    float xv = xb[(size_t)c * HW];
    const float* wr = crwT + c * NC;
#pragma unroll
    for (int o = 0; o < NC; o++) acc[o] = fmaf(wr[o], xv, acc[o]);
  }
  int lane = threadIdx.x & 63, wid = threadIdx.x >> 6;
  __shared__ float sred[4][128];
  float* yo = yraw + (size_t)b * NC * HW + pix;
#pragma unroll
  for (int o = 0; o < NC; o++) {
    float v = acc[o] + crb[o];
    yo[(size_t)o * HW] = v;
    float s = v, s2 = v * v;
#pragma unroll
    for (int k = 1; k < 64; k <<= 1) { s += __shfl_xor(s, k, 64); s2 += __shfl_xor(s2, k, 64); }
    if (lane == o) { sred[wid][o] = s; sred[wid][64 + o] = s2; }
  }
  __syncthreads();
  if (threadIdx.x < 128) {
    float t = sred[0][threadIdx.x] + sred[1][threadIdx.x] + sred[2][threadIdx.x] + sred[3][threadIdx.x];
    atomicAdd(&ws[O_CRS + threadIdx.x], t);
  }
}

// ---------------- LDS-tiled multi-dilation conv (MODE 0: bn1 stats, MODE 1: fuse) ----------------
template<int MODE>
__global__ __launch_bounds__(256) void k_conv(const float* __restrict__ yraw,
                                              const float* __restrict__ dww,
                                              const float* __restrict__ dwb,
                                              const float* __restrict__ crg,
                                              const float* __restrict__ crbe,
                                              const float* __restrict__ bn1g,
                                              const float* __restrict__ bn1b,
                                              const float* __restrict__ fusew,
                                              const float* __restrict__ fuseb,
                                              float* __restrict__ ws) {
  __shared__ float lds[LROWS * LROW];
  int blk = blockIdx.x;                       // 1024 = 8b * 64c * 2 halves
  int half = blk & 1, c = (blk >> 1) & 63, b = blk >> 7;
  int tid = threadIdx.x;
  const float inv = 1.0f / NPOSF;

  // cr-BN fold
  float m = ws[O_CRS + c] * inv;
  float v = ws[O_CRS + 64 + c] * inv - m * m;
  float s1 = crg[c] * rsqrtf(v + EPSV);
  float t1 = crbe[c] - m * s1;

  // conv weights + biases (wave-uniform)
  float kw[36];
#pragma unroll
  for (int d = 0; d < 4; d++)
#pragma unroll
    for (int t = 0; t < 9; t++) kw[d * 9 + t] = dww[((size_t)d * NC + c) * 9 + t];
  float bias[4];
#pragma unroll
  for (int d = 0; d < 4; d++) bias[d] = dwb[d * NC + c];

  // FUSE-mode folded bn1 params
  float fw[4], sdv[4], tdd[4], fb0 = 0.f;
  if (MODE == 1) {
#pragma unroll
    for (int d = 0; d < 4; d++) {
      float m1 = ws[O_BN1S + c * 4 + d] * inv;
      float v1 = ws[O_BN1S + 256 + c * 4 + d] * inv - m1 * m1;
      float sd = bn1g[c * 4 + d] * rsqrtf(v1 + EPSV);
      float td = bn1b[c * 4 + d] - m1 * sd;
      sdv[d] = sd;
      tdd[d] = fmaf(sd, bias[d], td);   // fold conv bias into bn1 shift
      fw[d] = fusew[c * 4 + d];
    }
    fb0 = fuseb[c];
  }

  // ---- stage: zero pads, then load 80 rows (halo clipped) with relu(bn) applied ----
  float4* lds4 = (float4*)lds;
#pragma unroll
  for (int k = 0; k < 12; k++) {
    int i = tid + k * 256;
    if (i < (LROWS * LROW) / 4) lds4[i] = make_float4(0.f, 0.f, 0.f, 0.f);
  }
  __syncthreads();
  int r0 = half * 64;
  const float4* yb4 = (const float4*)(yraw + (size_t)(b * NC + c) * HW);
#pragma unroll
  for (int k = 0; k < 10; k++) {
    int j = tid + k * 256;          // 2560 float4 = 80 rows * 32
    int l = j >> 5, c4 = j & 31;
    int g = r0 - 8 + l;
    if ((unsigned)g < 128u) {
      float4 vv = yb4[g * 32 + c4];
      vv.x = fmaxf(fmaf(s1, vv.x, t1), 0.f);
      vv.y = fmaxf(fmaf(s1, vv.y, t1), 0.f);
      vv.z = fmaxf(fmaf(s1, vv.z, t1), 0.f);
      vv.w = fmaxf(fmaf(s1, vv.w, t1), 0.f);
      *(float4*)&lds[l * LROW + 8 + c4 * 4] = vv;
    }
  }
  __syncthreads();

  // ---- compute: each thread 8 row-iters x 4 consecutive pixels ----
  int w0 = (tid & 31) * 4, h0 = tid >> 5, cb = w0 + 8;
  const int DIL[4] = {1, 2, 4, 8};

  float ss[4] = {0.f, 0.f, 0.f, 0.f}, s2[4] = {0.f, 0.f, 0.f, 0.f};  // stats mode
  float fs = 0.f, fs2 = 0.f;                                          // fuse mode
  float* fout = ws + O_FRAW + (size_t)(b * NC + c) * HW;

  for (int k = 0; k < 8; k++) {
    int lh = h0 + 8 * k;            // local row 0..63
    int r = lh + 8;                 // LDS row
    float od[4][4];
#pragma unroll
    for (int d = 0; d < 4; d++)
#pragma unroll
      for (int j = 0; j < 4; j++) od[d][j] = 0.f;

    // center row: 5 windows covering cb-8 .. cb+11
    {
      float4 A = *(const float4*)&lds[r * LROW + cb - 8];
      float4 B = *(const float4*)&lds[r * LROW + cb - 4];
      float4 C = *(const float4*)&lds[r * LROW + cb];
      float4 D = *(const float4*)&lds[r * LROW + cb + 4];
      float4 E = *(const float4*)&lds[r * LROW + cb + 8];
      float seg[20] = {A.x, A.y, A.z, A.w, B.x, B.y, B.z, B.w,
                       C.x, C.y, C.z, C.w, D.x, D.y, D.z, D.w,
                       E.x, E.y, E.z, E.w};
#pragma unroll
      for (int d = 0; d < 4; d++) {
        int dil = DIL[d];
#pragma unroll
        for (int j = 0; j < 4; j++) {
          float a = od[d][j];
          a = fmaf(kw[d * 9 + 3], seg[8 + j - dil], a);
          a = fmaf(kw[d * 9 + 4], seg[8 + j], a);
          a = fmaf(kw[d * 9 + 5], seg[8 + j + dil], a);
          od[d][j] = a;
        }
      }
    }
    // rows +-1, +-2, +-4: windows cb-4, cb, cb+4
#pragma unroll
    for (int di = 0; di < 3; di++) {
      int off = DIL[di];
#pragma unroll
      for (int sgn = 0; sgn < 2; sgn++) {
        int r2 = sgn ? r + off : r - off;
        int krow = sgn ? 6 : 0;
        float4 A = *(const float4*)&lds[r2 * LROW + cb - 4];
        float4 B = *(const float4*)&lds[r2 * LROW + cb];
        float4 C = *(const float4*)&lds[r2 * LROW + cb + 4];
        float sg[12] = {A.x, A.y, A.z, A.w, B.x, B.y, B.z, B.w, C.x, C.y, C.z, C.w};
#pragma unroll
        for (int j = 0; j < 4; j++) {
          float a = od[di][j];
          a = fmaf(kw[di * 9 + krow + 0], sg[j + 4 - off], a);
          a = fmaf(kw[di * 9 + krow + 1], sg[j + 4], a);
          a = fmaf(kw[di * 9 + krow + 2], sg[j + 4 + off], a);
          od[di][j] = a;
        }
      }
    }
    // rows +-8 (d=3): windows cb-8, cb, cb+8
#pragma unroll
    for (int sgn = 0; sgn < 2; sgn++) {
      int r2 = sgn ? r + 8 : r - 8;
      int krow = sgn ? 6 : 0;
      float4 A = *(const float4*)&lds[r2 * LROW + cb - 8];
      float4 B = *(const float4*)&lds[r2 * LROW + cb];
      float4 C = *(const float4*)&lds[r2 * LROW + cb + 8];
      float av[4] = {A.x, A.y, A.z, A.w};
      float bv[4] = {B.x, B.y, B.z, B.w};
      float cv[4] = {C.x, C.y, C.z, C.w};
#pragma unroll
      for (int j = 0; j < 4; j++) {
        float a = od[3][j];
        a = fmaf(kw[27 + krow + 0], av[j], a);
        a = fmaf(kw[27 + krow + 1], bv[j], a);
        a = fmaf(kw[27 + krow + 2], cv[j], a);
        od[3][j] = a;
      }
    }

    if (MODE == 0) {
#pragma unroll
      for (int d = 0; d < 4; d++)
#pragma unroll
        for (int j = 0; j < 4; j++) {
          float val = od[d][j] + bias[d];
          ss[d] += val;
          s2[d] += val * val;
        }
    } else {
      float4 f4;
      float fj[4];
#pragma unroll
      for (int j = 0; j < 4; j++) {
        float f = fb0;
#pragma unroll
        for (int d = 0; d < 4; d++)
          f = fmaf(fw[d], fmaxf(fmaf(sdv[d], od[d][j], tdd[d]), 0.f), f);
        fj[j] = f;
        fs += f;
        fs2 += f * f;
      }
      f4.x = fj[0]; f4.y = fj[1]; f4.z = fj[2]; f4.w = fj[3];
      *(float4*)&fout[(r0 + lh) * WROW + w0] = f4;
    }
  }

  // ---- reductions ----
  int lane = tid & 63, wid = tid >> 6;
  if (MODE == 0) {
    __shared__ float sred[4][8];
#pragma unroll
    for (int d = 0; d < 4; d++) {
      float s = ss[d], q = s2[d];
#pragma unroll
      for (int k = 1; k < 64; k <<= 1) { s += __shfl_xor(s, k, 64); q += __shfl_xor(q, k, 64); }
      if (lane == 0) { sred[wid][d] = s; sred[wid][4 + d] = q; }
    }
    __syncthreads();
    if (tid < 8) {
      float t = sred[0][tid] + sred[1][tid] + sred[2][tid] + sred[3][tid];
      int d = tid & 3, which = tid >> 2;
      atomicAdd(&ws[O_BN1S + which * 256 + c * 4 + d], t);
    }
  } else {
    __shared__ float sred[4][2];
    float s = fs, q = fs2;
#pragma unroll
    for (int k = 1; k < 64; k <<= 1) { s += __shfl_xor(s, k, 64); q += __shfl_xor(q, k, 64); }
    if (lane == 0) { sred[wid][0] = s; sred[wid][1] = q; }
    __syncthreads();
    if (tid < 2) {
      float t = sred[0][tid] + sred[1][tid] + sred[2][tid] + sred[3][tid];
      atomicAdd(&ws[O_BN2S + tid * 64 + c], t);
    }
  }
}

// ---------------- mb-BN stats on f = relu(bn2(f_raw)) ----------------
__global__ __launch_bounds__(256) void k_mb(const float* __restrict__ bn2g,
                                            const float* __restrict__ bn2b,
                                            float* __restrict__ ws) {
  int blk = blockIdx.x;            // 8192
  int plane = blk >> 4, sub = blk & 15;
  int c = plane & 63;
  const float inv = 1.0f / NPOSF;
  float m = ws[O_BN2S + c] * inv;
  float v = ws[O_BN2S + 64 + c] * inv - m * m;
  float s2v = bn2g[c] * rsqrtf(v + EPSV);
  float t2v = bn2b[c] - m * s2v;
  const float4* fp = (const float4*)(ws + O_FRAW + (size_t)plane * HW + sub * 1024);
  float4 vv = fp[threadIdx.x];
  float s = 0.f, ss = 0.f;
  {
    float f;
    f = fmaxf(fmaf(s2v, vv.x, t2v), 0.f); s += f; ss += f * f;
    f = fmaxf(fmaf(s2v, vv.y, t2v), 0.f); s += f; ss += f * f;
    f = fmaxf(fmaf(s2v, vv.z, t2v), 0.f); s += f; ss += f * f;
    f = fmaxf(fmaf(s2v, vv.w, t2v), 0.f); s += f; ss += f * f;
  }
  int lane = threadIdx.x & 63, wid = threadIdx.x >> 6;
  __shared__ float sred[4][2];
#pragma unroll
  for (int k = 1; k < 64; k <<= 1) { s += __shfl_xor(s, k, 64); ss += __shfl_xor(ss, k, 64); }
  if (lane == 0) { sred[wid][0] = s; sred[wid][1] = ss; }
  __syncthreads();
  if (threadIdx.x < 2) {
    float t = sred[0][threadIdx.x] + sred[1][threadIdx.x] + sred[2][threadIdx.x] + sred[3][threadIdx.x];
    atomicAdd(&ws[O_MBS + threadIdx.x * 64 + c], t);
  }
}

// ---------------- Gram of z + mean of z (for analytic final BN) ----------------
__global__ __launch_bounds__(256) void k_gram(const float* __restrict__ bn2g,
                                              const float* __restrict__ bn2b,
                                              const float* __restrict__ mbg,
                                              const float* __restrict__ mbb,
                                              float* __restrict__ ws) {
  __shared__ float zt[NC * 256];
  __shared__ float msum[4][NC];
  int tid = threadIdx.x, lane = tid & 63, wid = tid >> 6;
  int tile = blockIdx.x & 63, b = blockIdx.x >> 6;
  const float* fb = ws + O_FRAW + (size_t)b * NC * HW + tile * 256;
  const float inv = 1.0f / NPOSF;
  for (int c = 0; c < NC; c++) {
    float m2 = ws[O_BN2S + c] * inv;
    float v2 = ws[O_BN2S + 64 + c] * inv - m2 * m2;
    float s2v = bn2g[c] * rsqrtf(v2 + EPSV);
    float t2v = bn2b[c] - m2 * s2v;
    float m3 = ws[O_MBS + c] * inv;
    float v3 = ws[O_MBS + 64 + c] * inv - m3 * m3;
    float s3v = mbg[c] * rsqrtf(v3 + EPSV);
    float t3v = mbb[c] - m3 * s3v;
    float fv = fb[(size_t)c * HW + tid];
    float z = fmaxf(fmaf(s3v, fmaxf(fmaf(s2v, fv, t2v), 0.f), t3v), 0.f);
    zt[c * 256 + (tid ^ ((((unsigned)c >> 2) & 7u) << 2))] = z;
    float s = z;
#pragma unroll
    for (int k = 1; k < 64; k <<= 1) s += __shfl_xor(s, k, 64);
    if (lane == 0) msum[wid][c] = s;
  }
  __syncthreads();
  if (tid < NC) {
    float t = msum[0][tid] + msum[1][tid] + msum[2][tid] + msum[3][tid];
    atomicAdd(&ws[O_MZ + tid], t);
  }
  int tr = (tid & 15) * 4, tc = (tid >> 4) * 4;
  float g[4][4];
#pragma unroll
  for (int i = 0; i < 4; i++)
#pragma unroll
    for (int j = 0; j < 4; j++) g[i][j] = 0.f;
  for (int p = 0; p < 256; p += 4) {
    float4 av[4], bv[4];
#pragma unroll
    for (int i = 0; i < 4; i++) {
      int ca = tr + i, cb = tc + i;
      av[i] = *(const float4*)&zt[ca * 256 + (p ^ ((((unsigned)ca >> 2) & 7u) << 2))];
      bv[i] = *(const float4*)&zt[cb * 256 + (p ^ ((((unsigned)cb >> 2) & 7u) << 2))];
    }
#pragma unroll
    for (int i = 0; i < 4; i++)
#pragma unroll
      for (int j = 0; j < 4; j++) {
        g[i][j] = fmaf(av[i].x, bv[j].x, g[i][j]);
        g[i][j] = fmaf(av[i].y, bv[j].y, g[i][j]);
        g[i][j] = fmaf(av[i].z, bv[j].z, g[i][j]);
        g[i][j] = fmaf(av[i].w, bv[j].w, g[i][j]);
      }
  }
#pragma unroll
  for (int i = 0; i < 4; i++)
#pragma unroll
    for (int j = 0; j < 4; j++)
      atomicAdd(&ws[O_G + (tr + i) * 64 + (tc + j)], g[i][j]);
}

// ---------------- analytic ffbn + weight folding (LDS-staged, latency-fixed) ----------------
__global__ __launch_bounds__(256) void k_fold(const float* __restrict__ ffw,
                                              const float* __restrict__ ffb,
                                              const float* __restrict__ ffg,
                                              const float* __restrict__ ffbe,
                                              float* __restrict__ ws) {
  __shared__ float Gs[NC * NC];     // 16 KB: Gram matrix
  __shared__ float mzs[NC];
  int tid = threadIdx.x;
  const float inv = 1.0f / NPOSF;
  // cooperative stage: G (4096 floats) + mz (64 floats)
  float4* Gs4 = (float4*)Gs;
  const float4* Gg4 = (const float4*)(ws + O_G);
#pragma unroll
  for (int k = 0; k < 4; k++) Gs4[tid + k * 256] = Gg4[tid + k * 256];
  if (tid < NC) mzs[tid] = ws[O_MZ + tid] * inv;
  // per-thread ffw row -> registers
  int oc = tid;
  float w[NC];
#pragma unroll
  for (int c = 0; c < NC; c += 4) {
    float4 t = *(const float4*)&ffw[oc * NC + c];
    w[c] = t.x; w[c + 1] = t.y; w[c + 2] = t.z; w[c + 3] = t.w;
  }
  __syncthreads();
  // mean of pre-BN output
  float wm = 0.f;
  {
    float a0 = 0.f, a1 = 0.f, a2 = 0.f, a3 = 0.f;
#pragma unroll
    for (int c = 0; c < NC; c += 4) {
      a0 = fmaf(w[c], mzs[c], a0);
      a1 = fmaf(w[c + 1], mzs[c + 1], a1);
      a2 = fmaf(w[c + 2], mzs[c + 2], a2);
      a3 = fmaf(w[c + 3], mzs[c + 3], a3);
    }
    wm = (a0 + a1) + (a2 + a3);
  }
  float bias = ffb[oc];
  float mo = wm + bias;
  // quadratic form w^T G w from LDS (uniform-address broadcast reads)
  float e2s = 0.f;
  for (int c1 = 0; c1 < NC; c1++) {
    const float4* gr = (const float4*)&Gs[c1 * NC];
    float a0 = 0.f, a1 = 0.f, a2 = 0.f, a3 = 0.f;
#pragma unroll
    for (int q = 0; q < 16; q += 4) {
      float4 g0 = gr[q], g1 = gr[q + 1], g2 = gr[q + 2], g3 = gr[q + 3];
      a0 = fmaf(w[q * 4 + 0], g0.x, a0); a0 = fmaf(w[q * 4 + 1], g0.y, a0);
      a0 = fmaf(w[q * 4 + 2], g0.z, a0); a0 = fmaf(w[q * 4 + 3], g0.w, a0);
      a1 = fmaf(w[q * 4 + 4], g1.x, a1); a1 = fmaf(w[q * 4 + 5], g1.y, a1);
      a1 = fmaf(w[q * 4 + 6], g1.z, a1); a1 = fmaf(w[q * 4 + 7], g1.w, a1);
      a2 = fmaf(w[q * 4 + 8], g2.x, a2); a2 = fmaf(w[q * 4 + 9], g2.y, a2);
      a2 = fmaf(w[q * 4 + 10], g2.z, a2); a2 = fmaf(w[q * 4 + 11], g2.w, a2);
      a3 = fmaf(w[q * 4 + 12], g3.x, a3); a3 = fmaf(w[q * 4 + 13], g3.y, a3);
      a3 = fmaf(w[q * 4 + 14], g3.z, a3); a3 = fmaf(w[q * 4 + 15], g3.w, a3);
    }
    e2s = fmaf(w[c1], (a0 + a1) + (a2 + a3), e2s);
  }
  float e2 = e2s * inv + 2.f * bias * wm + bias * bias;
  float var = e2 - mo * mo;
  float s4 = ffg[oc] * rsqrtf(var + EPSV);
  float t4 = ffbe[oc] - mo * s4;
#pragma unroll
  for (int c = 0; c < NC; c++) ws[O_WFT + c * NOUT + oc] = s4 * w[c];
  ws[O_BF + oc] = fmaf(s4, bias, t4);
}

// ---------------- final: z -> folded 1x1 GEMM -> relu -> out ----------------
__global__ __launch_bounds__(256) void k_final(const float* __restrict__ bn2g,
                                               const float* __restrict__ bn2b,
                                               const float* __restrict__ mbg,
                                               const float* __restrict__ mbb,
                                               float* __restrict__ out,
                                               const float* __restrict__ ws) {
  __shared__ float zs[NC * 256];
  int tid = threadIdx.x;
  int p = blockIdx.x * 256 + tid;
  int b = p >> 14, pix = p & (HW - 1);
  const float* fb = ws + O_FRAW + (size_t)b * NC * HW + pix;
  const float inv = 1.0f / NPOSF;
  for (int c = 0; c < NC; c++) {
    float m2 = ws[O_BN2S + c] * inv;
    float v2 = ws[O_BN2S + 64 + c] * inv - m2 * m2;
    float s2v = bn2g[c] * rsqrtf(v2 + EPSV);
    float t2v = bn2b[c] - m2 * s2v;
    float m3 = ws[O_MBS + c] * inv;
    float v3 = ws[O_MBS + 64 + c] * inv - m3 * m3;
    float s3v = mbg[c] * rsqrtf(v3 + EPSV);
    float t3v = mbb[c] - m3 * s3v;
    float fv = fb[(size_t)c * HW];
    zs[c * 256 + tid] = fmaxf(fmaf(s3v, fmaxf(fmaf(s2v, fv, t2v), 0.f), t3v), 0.f);
  }
  float* ob = out + (size_t)b * NOUT * HW + pix;
  for (int ch = 0; ch < 4; ch++) {
    float acc[64];
#pragma unroll
    for (int j = 0; j < 64; j++) acc[j] = 0.f;
    const float* wf = ws + O_WFT + ch * 64;
    for (int c = 0; c < NC; c++) {
      float zv = zs[c * 256 + tid];
      const float* wr = wf + c * NOUT;
#pragma unroll
      for (int j = 0; j < 64; j++) acc[j] = fmaf(wr[j], zv, acc[j]);
    }
#pragma unroll
    for (int j = 0; j < 64; j++) {
      int oc = ch * 64 + j;
      ob[(size_t)oc * HW] = fmaxf(acc[j] + ws[O_BF + oc], 0.f);
    }
  }
}

extern "C" void kernel_launch(void* const* d_in, const int* in_sizes, int n_in,
                              void* d_out, int out_size, void* d_ws, size_t ws_size,
                              hipStream_t stream) {
  (void)in_sizes; (void)n_in; (void)out_size; (void)ws_size;
  const float* x     = (const float*)d_in[0];
  const float* crw   = (const float*)d_in[1];
  const float* crb   = (const float*)d_in[2];
  const float* crg   = (const float*)d_in[3];
  const float* crbe  = (const float*)d_in[4];
  const float* dww   = (const float*)d_in[5];
  const float* dwb   = (const float*)d_in[6];
  const float* bn1g  = (const float*)d_in[7];
  const float* bn1b  = (const float*)d_in[8];
  const float* fusew = (const float*)d_in[9];
  const float* fuseb = (const float*)d_in[10];
  const float* bn2g  = (const float*)d_in[11];
  const float* bn2b  = (const float*)d_in[12];
  const float* mbg   = (const float*)d_in[13];
  const float* mbb   = (const float*)d_in[14];
  const float* ffw   = (const float*)d_in[15];
  const float* ffb   = (const float*)d_in[16];
  const float* ffg   = (const float*)d_in[17];
  const float* ffbe  = (const float*)d_in[18];
  float* out = (float*)d_out;
  float* ws  = (float*)d_ws;
  float* yraw = out;  // first 8.4M floats of d_out used as scratch for y_raw

  hipMemsetAsync(ws, 0, ZERO_FLOATS * sizeof(float), stream);
  k_trans<<<64, 256, 0, stream>>>(crw, ws);
  k_cr<<<512, 256, 0, stream>>>(x, ws + O_CRWT, crb, yraw, ws);
  k_conv<0><<<1024, 256, 0, stream>>>(yraw, dww, dwb, crg, crbe, bn1g, bn1b, fusew, fuseb, ws);
  k_conv<1><<<1024, 256, 0, stream>>>(yraw, dww, dwb, crg, crbe, bn1g, bn1b, fusew, fuseb, ws);
  k_mb<<<8192, 256, 0, stream>>>(bn2g, bn2b, ws);
  k_gram<<<512, 256, 0, stream>>>(bn2g, bn2b, mbg, mbb, ws);
  k_fold<<<1, 256, 0, stream>>>(ffw, ffb, ffg, ffbe, ws);
  k_final<<<512, 256, 0, stream>>>(bn2g, bn2b, mbg, mbb, out, ws);
}